// Round 5
// baseline (952.000 us; speedup 1.0000x reference)
//
#include <hip/hip_runtime.h>
#include <hip/hip_cooperative_groups.h>

namespace cg = cooperative_groups;

// Problem constants (match reference)
#define PFN_NX     512
#define PFN_NY     512
#define PFN_P      (PFN_NX * PFN_NY)     // 262144 pillars (2^18)
#define PFN_B      4
#define PFN_NPTS   100000
#define PFN_C      64
#define PFN_TOTPTS (PFN_B * PFN_NPTS)    // 400,000 points
#define PFN_NTILE  (PFN_B * PFN_P / 64)  // 16384 tiles of 64 (b,pillar) bins
#define PFN_GRID   1024                  // cooperative grid (4 blocks/CU)

// Workspace (ints): counts[NTILE] | offsets[NTILE+1] | partials[64] | entries[TOTPTS]
// entry = (point_id << 6) | (bin & 63)   (point_id < 400000 -> 19 bits, fits)

__global__ __launch_bounds__(256, 4) void pfn_fused(const float* __restrict__ x,
                                                    const int*   __restrict__ idx,
                                                    float*       __restrict__ out,
                                                    int* __restrict__ counts,
                                                    int* __restrict__ offsets,
                                                    int* __restrict__ partials,
                                                    int* __restrict__ entries) {
    cg::grid_group grid = cg::this_grid();
    __shared__ __align__(16) float tile[64][65];   // [channel][local pillar]
    __shared__ int psh[64];
    const int tid  = threadIdx.x;
    const int gid  = blockIdx.x * 256 + tid;
    const int gsz  = PFN_GRID * 256;               // 262144
    const int wave = tid >> 6, lane = tid & 63;

    // ---- P0: zero tile counters (64 KB) ----
    if (gid < PFN_NTILE) counts[gid] = 0;
    grid.sync();

    // ---- P1: histogram over tiles ----
    for (int i = gid; i < PFN_TOTPTS; i += gsz) {
        int b = (unsigned)i / PFN_NPTS;
        atomicAdd(&counts[b * (PFN_P >> 6) + (idx[i] >> 6)], 1);
    }
    grid.sync();

    // ---- P2a: 64 blocks reduce 256-count chunks -> partials[64] ----
    int* s = (int*)tile;
    if (blockIdx.x < 64) {
        s[tid] = counts[blockIdx.x * 256 + tid];
        __syncthreads();
        for (int off = 128; off > 0; off >>= 1) {
            if (tid < off) s[tid] += s[tid + off];
            __syncthreads();
        }
        if (tid == 0) partials[blockIdx.x] = s[0];
    }
    grid.sync();

    // ---- P2b: 64 blocks produce exclusive offsets ----
    if (blockIdx.x < 64) {
        if (tid < 64) {
            int v = partials[tid];                 // wave-0 inclusive scan
            for (int off = 1; off < 64; off <<= 1) {
                int u = __shfl_up(v, off);
                if (lane >= off) v += u;
            }
            psh[tid] = v;
        }
        __syncthreads();
        const int base = (blockIdx.x == 0) ? 0 : psh[blockIdx.x - 1];
        int c = counts[blockIdx.x * 256 + tid];
        s[tid] = c;
        __syncthreads();
        for (int off = 1; off < 256; off <<= 1) {  // Hillis-Steele inclusive
            int add = (tid >= off) ? s[tid - off] : 0;
            __syncthreads();
            s[tid] += add;
            __syncthreads();
        }
        offsets[blockIdx.x * 256 + tid] = base + s[tid] - c;
        if (blockIdx.x == 63 && tid == 255) offsets[PFN_NTILE] = base + s[255];
    }
    grid.sync();

    // ---- P3: reorder points into tile-grouped entry list ----
    for (int i = gid; i < PFN_TOTPTS; i += gsz) {
        int b = (unsigned)i / PFN_NPTS;
        int v = idx[i];
        int t = b * (PFN_P >> 6) + (v >> 6);
        int old = atomicSub(&counts[t], 1);        // counts consumed as cursor
        entries[offsets[t] + old - 1] = (i << 6) | (v & 63);
    }
    grid.sync();

    // ---- P4: gather. One tile (64 bins) per block iteration. ----
    for (int T = blockIdx.x; T < PFN_NTILE; T += PFN_GRID) {
        for (int z = tid; z < 1040; z += 256)      // zero 64x65 floats
            ((float4*)tile)[z] = make_float4(0.f, 0.f, 0.f, 0.f);
        __syncthreads();

        int se = (lane < 2) ? offsets[T + lane] : 0;
        const int start = __shfl(se, 0);
        const int end   = __shfl(se, 1);

        for (int base0 = start; base0 < end; base0 += 64) {
            const int cw = min(64, end - base0);
            int ent = (lane < cw) ? entries[base0 + lane] : 0;
            // waves split the entry list; ds_add_f32 handles cross-wave dups.
            // banks: (lane*65 + bl) % 32 = (lane+bl) % 32 -> 2-way, free.
            for (int e = wave; e < cw; e += 4) {
                const int ex = __shfl(ent, e);
                const int bl = ex & 63;
                const int pi = ex >> 6;
                atomicAdd(&tile[lane][bl], x[((size_t)pi << 6) + lane]);
            }
        }
        __syncthreads();

        const int    b       = T >> 12;            // tile / (P/64)
        const int    p0      = (T << 6) & (PFN_P - 1);
        const size_t outBase = (size_t)b << 24;    // b * 64 * P
#pragma unroll
        for (int k = 0; k < 4; ++k) {
            const int id = k * 256 + tid;
            const int c  = id >> 4;
            const int ii = id & 15;
            float4 v;
            v.x = tile[c][4 * ii + 0];
            v.y = tile[c][4 * ii + 1];
            v.z = tile[c][4 * ii + 2];
            v.w = tile[c][4 * ii + 3];
            *(float4*)(out + outBase + ((size_t)c << 18) + p0 + 4 * ii) = v;
        }
        __syncthreads();                           // tile reused next iter
    }
}

extern "C" void kernel_launch(void* const* d_in, const int* in_sizes, int n_in,
                              void* d_out, int out_size, void* d_ws, size_t ws_size,
                              hipStream_t stream) {
    const float* x   = (const float*)d_in[0];   // (B, N, C) f32
    const int*   idx = (const int*)  d_in[1];   // (B, N) int32
    float*       out = (float*)d_out;           // (B, C, NX, NY) f32

    int* counts   = (int*)d_ws;                 // [NTILE]
    int* offsets  = counts + PFN_NTILE;         // [NTILE + 1]
    int* partials = offsets + PFN_NTILE + 1;    // [64]
    int* entries  = partials + 64;              // [TOTPTS]

    void* args[] = {(void*)&x, (void*)&idx, (void*)&out,
                    (void*)&counts, (void*)&offsets, (void*)&partials, (void*)&entries};
    hipLaunchCooperativeKernel((const void*)pfn_fused, dim3(PFN_GRID), dim3(256),
                               args, 0, stream);
}

// Round 6
// 389.800 us; speedup vs baseline: 2.4423x; 2.4423x over previous
//
#include <hip/hip_runtime.h>

// Problem constants (match reference)
#define PFN_NX     512
#define PFN_NY     512
#define PFN_P      (PFN_NX * PFN_NY)     // 262144 pillars (2^18)
#define PFN_B      4
#define PFN_NPTS   100000
#define PFN_C      64
#define PFN_NBIN   (PFN_B * PFN_P)       // 1,048,576 (b,pillar) bins
#define PFN_TOTPTS (PFN_B * PFN_NPTS)    // 400,000 points

// Workspace layout (ints):
//   counts  [NBIN]      : histogram (memset to 0), consumed as cursor by reorder
//   offsets [NBIN+1]    : exclusive scan + sentinel
//   partials[1024]      : per-1024-chunk sums
//   order   [TOTPTS]    : point ids grouped by (b,pillar)

// one int atomic per point into a 4 MB counter array (L2-resident)
__global__ __launch_bounds__(256) void pfn_hist(const int* __restrict__ idx,
                                                int* __restrict__ counts) {
    int pi = blockIdx.x * 256 + threadIdx.x;
    if (pi >= PFN_TOTPTS) return;
    int b = (unsigned)pi / PFN_NPTS;
    atomicAdd(&counts[b * PFN_P + idx[pi]], 1);
}

// level-1: sum each 1024-count chunk -> partials[1024]
__global__ __launch_bounds__(256) void pfn_block_reduce(const int4* __restrict__ counts4,
                                                        int* __restrict__ partials) {
    __shared__ int s[256];
    int t = threadIdx.x, g = blockIdx.x;
    int4 v = counts4[g * 256 + t];
    s[t] = v.x + v.y + v.z + v.w;
    __syncthreads();
    for (int off = 128; off > 0; off >>= 1) {
        if (t < off) s[t] += s[t + off];
        __syncthreads();
    }
    if (t == 0) partials[g] = s[0];
}

// fused level-2+3: every WG redundantly scans the 1024 partials (4 KB, L2-hot)
// to get its own chunk base, then scans its own 1024-count chunk -> offsets[].
__global__ __launch_bounds__(256) void pfn_scan(const int4* __restrict__ counts4,
                                                const int*  __restrict__ partials,
                                                int* __restrict__ offsets) {
    __shared__ int s[256];
    __shared__ int base_sh;
    const int t = threadIdx.x, g = blockIdx.x;

    // --- phase 1: chunk base from partials ---
    int4 pv = ((const int4*)partials)[t];
    int psum = pv.x + pv.y + pv.z + pv.w;
    s[t] = psum;
    __syncthreads();
    for (int off = 1; off < 256; off <<= 1) {
        int add = (t >= off) ? s[t - off] : 0;
        __syncthreads();
        s[t] += add;
        __syncthreads();
    }
    const int q = g >> 2, r = g & 3;
    if (t == q) {
        int excl = s[q] - psum;          // exclusive prefix of partials[4q]
        if (r > 0) excl += pv.x;
        if (r > 1) excl += pv.y;
        if (r > 2) excl += pv.z;
        base_sh = excl;
    }
    if (g == 0 && t == 255) offsets[PFN_NBIN] = s[255];  // sentinel = TOTPTS
    __syncthreads();
    const int base = base_sh;
    __syncthreads();                     // s[] about to be reused

    // --- phase 2: scan own chunk ---
    int4 v = counts4[g * 256 + t];
    int sum = v.x + v.y + v.z + v.w;
    s[t] = sum;
    __syncthreads();
    for (int off = 1; off < 256; off <<= 1) {
        int add = (t >= off) ? s[t - off] : 0;
        __syncthreads();
        s[t] += add;
        __syncthreads();
    }
    int excl = s[t] - sum + base;
    int4 o;
    o.x = excl;
    o.y = excl + v.x;
    o.z = excl + v.x + v.y;
    o.w = excl + v.x + v.y + v.z;
    ((int4*)offsets)[g * 256 + t] = o;
}

// group point ids by bin; atomicSub consumes counts as a per-bin cursor
__global__ __launch_bounds__(256) void pfn_reorder(const int* __restrict__ idx,
                                                   const int* __restrict__ offsets,
                                                   int* __restrict__ counts,
                                                   int* __restrict__ order) {
    int pi = blockIdx.x * 256 + threadIdx.x;
    if (pi >= PFN_TOTPTS) return;
    int b = (unsigned)pi / PFN_NPTS;
    int bp = b * PFN_P + idx[pi];
    int old = atomicSub(&counts[bp], 1);        // old in [cnt..1]
    order[offsets[bp] + old - 1] = pi;
}

// ---------------------------------------------------------------------------
// Gather: one workgroup per 64 consecutive bins; wave owns 16 bins,
// lane = channel for the accumulate phase (256 B coalesced x reads).
// R6 change (ILP): instead of a dynamic per-bin loop whose loads serialize
// behind vmcnt(0), each wave precomputes its points' bins, then processes
// points in unrolled batches of 8: 8 INDEPENDENT x-row loads issued
// back-to-back (one memory latency amortized over 8), then 8 short LDS
// read-modify-writes into the wave's own 16 tile columns (non-atomic;
// ownership makes it race-free, same-wave DS ordering handles duplicates).
// LDS tile is [channel][local pillar] with +1 pad; epilogue writes float4
// (1 KB/wave/instr). Every output element written exactly once.
// ---------------------------------------------------------------------------
__global__ __launch_bounds__(256) void pfn_gather(const float* __restrict__ x,
                                                  const int*   __restrict__ offsets,
                                                  const int*   __restrict__ order,
                                                  float*       __restrict__ out) {
    __shared__ float tile[64][65];       // [channel][local pillar], +1 pad
    const int g    = blockIdx.x;         // [0, NBIN/64)
    const int bp0  = g << 6;
    const int b    = bp0 >> 18;          // / P
    const int p0   = bp0 & (PFN_P - 1);
    const int wave = threadIdx.x >> 6;
    const int lane = threadIdx.x & 63;
    const int wb0  = bp0 + wave * 16;    // this wave's first bin

    int off_l = 0;
    if (lane <= 16) off_l = offsets[wb0 + lane];
    const int o_base = __shfl(off_l, 0);
    const int o_end  = __shfl(off_l, 16);
    const int cnt    = o_end - o_base;

    if (cnt <= 64) {
        // zero this wave's 16 columns (2-way banks, free)
#pragma unroll
        for (int k = 0; k < 16; ++k) tile[lane][wave * 16 + k] = 0.f;

        // one coalesced prefetch of the wave's order entries
        int ord_l = (lane < cnt) ? order[o_base + lane] : 0;

        // lane t (< cnt) computes the bin (0..15) of point t:
        // bin = #{ j in 1..15 : offsets[wb0+j]-o_base <= t }
        int myBin = 0;
#pragma unroll
        for (int j = 1; j < 16; ++j)
            myBin += ((__shfl(off_l, j) - o_base) <= lane) ? 1 : 0;

        for (int b0 = 0; b0 < cnt; b0 += 8) {
            float pre[8];
            int   col[8];
#pragma unroll
            for (int k = 0; k < 8; ++k) {
                const int t = b0 + k;
                if (t < cnt) {
                    const int pi = __shfl(ord_l, t);       // readlane (uniform t)
                    col[k] = wave * 16 + __shfl(myBin, t);
                    pre[k] = x[((size_t)pi << 6) + lane];  // independent loads
                }
            }
#pragma unroll
            for (int k = 0; k < 8; ++k) {
                const int t = b0 + k;
                if (t < cnt) tile[lane][col[k]] += pre[k]; // short LDS RMW
            }
        }
    } else {
        // slow path (statistically never: E[cnt]=6.1): direct per-bin loop
        for (int j = 0; j < 16; ++j) {
            const int start = __shfl(off_l, j);
            const int end   = __shfl(off_l, j + 1);
            float s = 0.f;
            for (int t = start; t < end; ++t) {
                const int pi = order[t];
                s += x[((size_t)pi << 6) + lane];
            }
            tile[lane][wave * 16 + j] = s;
        }
    }
    __syncthreads();

    // epilogue: 1024 float4 stores, 4 per thread; 16 lanes cover one channel
    // row (256 B contiguous), 4 channels per wave per iteration.
    const size_t outBase = (size_t)b << 24;          // b * 64 * P
#pragma unroll
    for (int k = 0; k < 4; ++k) {
        const int id = k * 256 + threadIdx.x;        // [0, 1024)
        const int c  = id >> 4;                      // channel
        const int i  = id & 15;                      // float4 index in p
        float4 v;
        v.x = tile[c][4 * i + 0];
        v.y = tile[c][4 * i + 1];
        v.z = tile[c][4 * i + 2];
        v.w = tile[c][4 * i + 3];
        *(float4*)(out + outBase + ((size_t)c << 18) + p0 + 4 * i) = v;
    }
}

extern "C" void kernel_launch(void* const* d_in, const int* in_sizes, int n_in,
                              void* d_out, int out_size, void* d_ws, size_t ws_size,
                              hipStream_t stream) {
    const float* x   = (const float*)d_in[0];   // (B, N, C) f32
    const int*   idx = (const int*)  d_in[1];   // (B, N) int32
    float*       out = (float*)d_out;           // (B, C, NX, NY) f32

    int* counts   = (int*)d_ws;                 // [NBIN]
    int* offsets  = counts + PFN_NBIN;          // [NBIN + 1]
    int* partials = offsets + PFN_NBIN + 1;     // [1024]
    int* order    = partials + 1024;            // [TOTPTS]

    // 1) zero histogram (ws is poisoned to 0xAA each launch) — memset node
    hipMemsetAsync(counts, 0, (size_t)PFN_NBIN * sizeof(int), stream);
    // 2) histogram
    pfn_hist<<<(PFN_TOTPTS + 255) / 256, 256, 0, stream>>>(idx, counts);
    // 3) per-chunk sums
    pfn_block_reduce<<<1024, 256, 0, stream>>>((const int4*)counts, partials);
    // 4) fused two-level exclusive scan -> offsets
    pfn_scan<<<1024, 256, 0, stream>>>((const int4*)counts, partials, offsets);
    // 5) group point ids by bin
    pfn_reorder<<<(PFN_TOTPTS + 255) / 256, 256, 0, stream>>>(idx, offsets, counts, order);
    // 6) gather + transpose + single coalesced float4 write of the whole grid
    pfn_gather<<<PFN_NBIN / 64, 256, 0, stream>>>(x, offsets, order, out);
}